// Round 1
// baseline (192.668 us; speedup 1.0000x reference)
//
#include <hip/hip_runtime.h>
#include <hip/hip_bf16.h>
#include <stdint.h>

// Problem constants
#define D_MODEL 1024
#define BATCH   4
#define SEQ     4096
#define M_TOTAL (BATCH*SEQ)   // 16384
#define KDIM    D_MODEL

// Scan chunking
#define NC 128
#define CL (SEQ/NC)           // 32

// GEMM tiling (m97 structure)
#define BM 128
#define BN 128
#define BK 32

typedef __bf16 bf16x8 __attribute__((ext_vector_type(8)));
typedef float  f32x4  __attribute__((ext_vector_type(4)));

static __device__ __forceinline__ unsigned short f2bf(float f) {
  unsigned u = __builtin_bit_cast(unsigned, f);
  u += 0x7FFFu + ((u >> 16) & 1u);     // round-to-nearest-even
  return (unsigned short)(u >> 16);
}

// ---------------- K0a: x (fp32) -> bf16 ----------------
__global__ __launch_bounds__(256) void k_cvt_x(const float* __restrict__ x,
                                               unsigned short* __restrict__ xb) {
  int i = blockIdx.x * 256 + threadIdx.x;          // each handles 4 elems
  float4 v = ((const float4*)x)[i];
  ushort4 o;
  o.x = f2bf(v.x); o.y = f2bf(v.y); o.z = f2bf(v.z); o.w = f2bf(v.w);
  ((ushort4*)xb)[i] = o;
}

// ---------------- K0b: W (fp32 [d][e]) -> bf16 transposed [e][d] ----------------
__global__ void k_cvt_wT(const float* __restrict__ Wz, const float* __restrict__ Wh,
                         unsigned short* __restrict__ WzT, unsigned short* __restrict__ WhT) {
  __shared__ float tile[32][33];
  const float* W = blockIdx.z ? Wh : Wz;
  unsigned short* O = blockIdx.z ? WhT : WzT;
  int bx = blockIdx.x * 32;   // e base (cols of W)
  int by = blockIdx.y * 32;   // d base (rows of W)
  int tx = threadIdx.x, ty = threadIdx.y; // 32 x 8
  for (int yy = ty; yy < 32; yy += 8)
    tile[yy][tx] = W[(size_t)(by + yy) * D_MODEL + bx + tx];
  __syncthreads();
  for (int yy = ty; yy < 32; yy += 8)
    O[(size_t)(bx + yy) * D_MODEL + by + tx] = f2bf(tile[tx][yy]);
}

// ---------------- K1: dual GEMM  P = x@Wz,  Q = x@Wh (bf16 MFMA, fp32 out) -------
// grid (128, 16): x = M-block, y = N-block (0..7 -> Wz->P, 8..15 -> Wh->Q)
__global__ __launch_bounds__(256) void k_gemm_dual(
    const unsigned short* __restrict__ xb,    // [M][K] bf16
    const unsigned short* __restrict__ WzT,   // [N][K] bf16 (transposed W)
    const unsigned short* __restrict__ WhT,
    float* __restrict__ P, float* __restrict__ Q)
{
  __shared__ unsigned short As[BM * BK];   // [m][k], rows of 64 B, 8 KB
  __shared__ unsigned short Bs[BN * BK];   // [n][k], 8 KB
  const int tid  = threadIdx.x;
  const int wave = tid >> 6;
  const int lane = tid & 63;
  const int bm = blockIdx.x;
  const int bn = blockIdx.y;
  const unsigned short* Wt = (bn < 8) ? WzT : WhT;
  float* Cout = (bn < 8) ? P : Q;
  const int n0 = (bn & 7) * BN;
  const int m0 = bm * BM;

  const int wr = wave >> 1;            // wave row (0..1), 64 rows each
  const int wc = wave & 1;             // wave col (0..1), 64 cols each
  const int lr = lane & 15;
  const int lkB = (lane >> 4) * 16;    // byte offset of this lane's k-chunk (8 bf16)

  f32x4 acc[4][4];
  #pragma unroll
  for (int i = 0; i < 4; ++i)
    #pragma unroll
    for (int j = 0; j < 4; ++j) acc[i][j] = (f32x4){0.f, 0.f, 0.f, 0.f};

  // staging: tile = 512 chunks of 16 B; chunk c -> row c>>2, k-subchunk c&3
  const int c0 = tid;         // chunks 0..255
  const int c1 = tid + 256;   // chunks 256..511
  const int r0 = c0 >> 2, kc0 = (c0 & 3) * 8;
  const int r1 = c1 >> 2, kc1 = (c1 & 3) * 8;

  for (int kt = 0; kt < KDIM; kt += BK) {
    const unsigned short* gA0 = xb + (size_t)(m0 + r0) * KDIM + kt + kc0;
    const unsigned short* gA1 = xb + (size_t)(m0 + r1) * KDIM + kt + kc1;
    const unsigned short* gB0 = Wt + (size_t)(n0 + r0) * KDIM + kt + kc0;
    const unsigned short* gB1 = Wt + (size_t)(n0 + r1) * KDIM + kt + kc1;
    __builtin_amdgcn_global_load_lds(
        (const __attribute__((address_space(1))) unsigned int*)gA0,
        (__attribute__((address_space(3))) unsigned int*)((char*)As + wave * 1024),
        16, 0, 0);
    __builtin_amdgcn_global_load_lds(
        (const __attribute__((address_space(1))) unsigned int*)gA1,
        (__attribute__((address_space(3))) unsigned int*)((char*)As + 4096 + wave * 1024),
        16, 0, 0);
    __builtin_amdgcn_global_load_lds(
        (const __attribute__((address_space(1))) unsigned int*)gB0,
        (__attribute__((address_space(3))) unsigned int*)((char*)Bs + wave * 1024),
        16, 0, 0);
    __builtin_amdgcn_global_load_lds(
        (const __attribute__((address_space(1))) unsigned int*)gB1,
        (__attribute__((address_space(3))) unsigned int*)((char*)Bs + 4096 + wave * 1024),
        16, 0, 0);
    __syncthreads();   // compiler drains vmcnt before barrier

    bf16x8 af[4], bfr[4];
    #pragma unroll
    for (int i = 0; i < 4; ++i)
      af[i] = *(const bf16x8*)((const char*)As + (wr*64 + i*16 + lr) * (BK*2) + lkB);
    #pragma unroll
    for (int j = 0; j < 4; ++j)
      bfr[j] = *(const bf16x8*)((const char*)Bs + (wc*64 + j*16 + lr) * (BK*2) + lkB);
    #pragma unroll
    for (int i = 0; i < 4; ++i)
      #pragma unroll
      for (int j = 0; j < 4; ++j)
        acc[i][j] = __builtin_amdgcn_mfma_f32_16x16x32_bf16(af[i], bfr[j], acc[i][j], 0, 0, 0);
    __syncthreads();
  }

  // epilogue: C/D layout col = lane&15, row = 4*(lane>>4) + reg
  const int cb = lane & 15;
  const int rb = (lane >> 4) * 4;
  #pragma unroll
  for (int i = 0; i < 4; ++i) {
    #pragma unroll
    for (int j = 0; j < 4; ++j) {
      const size_t col = (size_t)(n0 + wc*64 + j*16 + cb);
      const size_t rowbase = (size_t)(m0 + wr*64 + i*16 + rb);
      #pragma unroll
      for (int r = 0; r < 4; ++r)
        Cout[(rowbase + r) * D_MODEL + col] = acc[i][j][r];
    }
  }
}

// ---------------- K2: per-chunk scan aggregates ----------------
// grid = BATCH*NC blocks, 256 threads, 4 d-values per thread (float4)
__global__ __launch_bounds__(256) void k_scan_agg(
    const float* __restrict__ P, const float* __restrict__ Q,
    const float* __restrict__ bz, const float* __restrict__ bh,
    float* __restrict__ Aagg, float* __restrict__ Bagg)
{
  int c = blockIdx.x & (NC - 1);
  int b = blockIdx.x >> 7;               // NC = 128
  int d = threadIdx.x * 4;
  f32x4 vbz = *(const f32x4*)(bz + d);
  f32x4 vbh = *(const f32x4*)(bh + d);
  f32x4 A = {1.f, 1.f, 1.f, 1.f}, Bv = {0.f, 0.f, 0.f, 0.f};
  size_t base = ((size_t)b * SEQ + (size_t)c * CL) * D_MODEL + d;
  for (int t = 0; t < CL; ++t) {
    f32x4 p = *(const f32x4*)(P + base + (size_t)t * D_MODEL);
    f32x4 q = *(const f32x4*)(Q + base + (size_t)t * D_MODEL);
    #pragma unroll
    for (int r = 0; r < 4; ++r) {
      float z = 1.f / (1.f + __expf(-(p[r] + vbz[r])));
      float a = 1.f - z;
      float bb = z * (q[r] + vbh[r]);
      Bv[r] = a * Bv[r] + bb;
      A[r]  = a * A[r];
    }
  }
  size_t o = ((size_t)b * NC + c) * D_MODEL + d;
  *(f32x4*)(Aagg + o) = A;
  *(f32x4*)(Bagg + o) = Bv;
}

// ---------------- K3: scan across chunk aggregates -> per-chunk entry prefix ----
__global__ __launch_bounds__(256) void k_scan_chunks(
    const float* __restrict__ Aagg, const float* __restrict__ Bagg,
    float* __restrict__ Pref)
{
  int idx = blockIdx.x * 256 + threadIdx.x;  // 0..4095 = b*1024 + d
  int b = idx >> 10, d = idx & 1023;
  float h = 0.f;
  for (int cc = 0; cc < NC; ++cc) {
    size_t o = ((size_t)b * NC + cc) * D_MODEL + d;
    Pref[o] = h;
    h = Aagg[o] * h + Bagg[o];
  }
}

// ---------------- K4: apply scan, write h into Q (= d_out, in-place) ------------
__global__ __launch_bounds__(256) void k_scan_apply(
    const float* __restrict__ P, float* __restrict__ Q,
    const float* __restrict__ bz, const float* __restrict__ bh,
    const float* __restrict__ Pref)
{
  int c = blockIdx.x & (NC - 1);
  int b = blockIdx.x >> 7;
  int d = threadIdx.x * 4;
  f32x4 vbz = *(const f32x4*)(bz + d);
  f32x4 vbh = *(const f32x4*)(bh + d);
  f32x4 h = *(const f32x4*)(Pref + ((size_t)b * NC + c) * D_MODEL + d);
  size_t base = ((size_t)b * SEQ + (size_t)c * CL) * D_MODEL + d;
  for (int t = 0; t < CL; ++t) {
    f32x4 p = *(const f32x4*)(P + base + (size_t)t * D_MODEL);
    f32x4 q = *(const f32x4*)(Q + base + (size_t)t * D_MODEL);
    #pragma unroll
    for (int r = 0; r < 4; ++r) {
      float z = 1.f / (1.f + __expf(-(p[r] + vbz[r])));
      float a = 1.f - z;
      h[r] = a * h[r] + z * (q[r] + vbh[r]);
    }
    *(f32x4*)(Q + base + (size_t)t * D_MODEL) = h;
  }
}

extern "C" void kernel_launch(void* const* d_in, const int* in_sizes, int n_in,
                              void* d_out, int out_size, void* d_ws, size_t ws_size,
                              hipStream_t stream)
{
  const float* x  = (const float*)d_in[0];
  const float* Wz = (const float*)d_in[1];
  const float* bz = (const float*)d_in[2];
  const float* Wh = (const float*)d_in[3];
  const float* bh = (const float*)d_in[4];

  char* ws = (char*)d_ws;
  // workspace layout (bytes)
  unsigned short* xb  = (unsigned short*)(ws);               // 33,554,432
  unsigned short* WzT = (unsigned short*)(ws + 33554432);    //  2,097,152
  unsigned short* WhT = (unsigned short*)(ws + 35651584);    //  2,097,152
  float* P    = (float*)(ws + 37748736);                     // 67,108,864
  float* Aagg = (float*)(ws + 104857600);                    //  2,097,152
  float* Bagg = (float*)(ws + 106954752);                    //  2,097,152
  float* Pref = (float*)(ws + 109051904);                    //  2,097,152
  float* Q = (float*)d_out;                                  // h-preact, then h (in-place)

  k_cvt_x<<<M_TOTAL * D_MODEL / 4 / 256, 256, 0, stream>>>(x, xb);
  k_cvt_wT<<<dim3(32, 32, 2), dim3(32, 8), 0, stream>>>(Wz, Wh, WzT, WhT);
  k_gemm_dual<<<dim3(M_TOTAL / BM, 16), 256, 0, stream>>>(xb, WzT, WhT, P, Q);
  k_scan_agg<<<BATCH * NC, 256, 0, stream>>>(P, Q, bz, bh, Aagg, Bagg);
  k_scan_chunks<<<BATCH * D_MODEL / 256, 256, 0, stream>>>(Aagg, Bagg, Pref);
  k_scan_apply<<<BATCH * NC, 256, 0, stream>>>(P, Q, bz, bh, Pref);
}

// Round 2
// 162.392 us; speedup vs baseline: 1.1864x; 1.1864x over previous
//
#include <hip/hip_runtime.h>
#include <hip/hip_bf16.h>
#include <stdint.h>

// Problem constants
#define D_MODEL 1024
#define BATCH   4
#define SEQ     4096
#define M_TOTAL (BATCH*SEQ)   // 16384
#define KDIM    D_MODEL
#define NTOT    2048          // combined N (z cols 0..1023, h cols 1024..2047)

// Scan chunking
#define NC 128
#define CL (SEQ/NC)           // 32

// GEMM tiling: 256x256 tile, BK=32, 8 waves, triple-buffered LDS
#define BM 256
#define BN 256
#define BK 32
#define NT (KDIM/BK)          // 32 K-tiles

typedef __bf16 bf16x8 __attribute__((ext_vector_type(8)));
typedef float  f32x4  __attribute__((ext_vector_type(4)));
typedef unsigned short u16x4 __attribute__((ext_vector_type(4)));

static __device__ __forceinline__ unsigned short f2bf(float f) {
  unsigned u = __builtin_bit_cast(unsigned, f);
  u += 0x7FFFu + ((u >> 16) & 1u);     // round-to-nearest-even
  return (unsigned short)(u >> 16);
}
static __device__ __forceinline__ float bf2f(unsigned short u) {
  return __builtin_bit_cast(float, (unsigned)u << 16);
}

// ---------------- K0a: x (fp32) -> bf16 ----------------
__global__ __launch_bounds__(256) void k_cvt_x(const float* __restrict__ x,
                                               unsigned short* __restrict__ xb) {
  int i = blockIdx.x * 256 + threadIdx.x;          // 4 elems each
  float4 v = ((const float4*)x)[i];
  ushort4 o;
  o.x = f2bf(v.x); o.y = f2bf(v.y); o.z = f2bf(v.z); o.w = f2bf(v.w);
  ((ushort4*)xb)[i] = o;
}

// ---------------- K0b: W (fp32 [d][e]) -> bf16 transposed [e][d], into Wall ----
__global__ void k_cvt_wT(const float* __restrict__ Wz, const float* __restrict__ Wh,
                         unsigned short* __restrict__ WzT, unsigned short* __restrict__ WhT) {
  __shared__ float tile[32][33];
  const float* W = blockIdx.z ? Wh : Wz;
  unsigned short* O = blockIdx.z ? WhT : WzT;
  int bx = blockIdx.x * 32;   // e base
  int by = blockIdx.y * 32;   // d base
  int tx = threadIdx.x, ty = threadIdx.y; // 32 x 8
  for (int yy = ty; yy < 32; yy += 8)
    tile[yy][tx] = W[(size_t)(by + yy) * D_MODEL + bx + tx];
  __syncthreads();
  for (int yy = ty; yy < 32; yy += 8)
    O[(size_t)(bx + yy) * D_MODEL + by + tx] = f2bf(tile[tx][yy]);
}

// ---------------- K1: GEMM  [P|Q](bf16) = xb @ Wall^T --------------------------
// 256x256 tile, BK=32, 8 waves (2M x 4N), per-wave out 128x64.
// LDS: 3 buffers x (A 16KB + B 16KB), fragment-major layout [kchunk][row][16B]
//   -> conflict-free ds_read_b128 AND linear global_load_lds dest.
// Pipeline: prefetch 2 K-tiles ahead, loop wait = vmcnt(4) (never 0 until tail),
// raw s_barrier (no implicit drain), setprio around MFMA clusters.
__global__ __launch_bounds__(512, 2) void k_gemm8(
    const unsigned short* __restrict__ xb,    // [M][K] bf16
    const unsigned short* __restrict__ Wall,  // [2048][K] bf16 ([WzT;WhT])
    unsigned short* __restrict__ P, unsigned short* __restrict__ Q)
{
  __shared__ __attribute__((aligned(16))) unsigned short lds[3 * 16384]; // 96 KB

  const int tid  = threadIdx.x;
  const int wave = tid >> 6;
  const int lane = tid & 63;
  const int m0 = blockIdx.x * BM;
  const int n0 = blockIdx.y * BN;
  const int wr = wave >> 2;            // 0..1  (128 rows each)
  const int wc = wave & 3;             // 0..3  (64 cols each)
  const int lr = lane & 15;
  const int lc = lane >> 4;            // k-chunk 0..3

  // staging pair coords (wave-uniform): pair p -> chunk p>>2, rowblock p&3
  const int p0 = wave * 2, p1 = wave * 2 + 1;
  const int c0 = p0 >> 2, rb0 = p0 & 3;
  const int c1 = p1 >> 2, rb1 = p1 & 3;

  f32x4 acc[8][4];
  #pragma unroll
  for (int i = 0; i < 8; ++i)
    #pragma unroll
    for (int j = 0; j < 4; ++j) acc[i][j] = (f32x4){0.f, 0.f, 0.f, 0.f};

  auto stage = [&](int kt, int bufb) {
    const int kb = kt * BK;
    unsigned short* ldsA = &lds[bufb * 16384];
    unsigned short* ldsB = ldsA + 8192;
    const unsigned short* a0 = xb   + (size_t)(m0 + rb0*64 + lane) * KDIM + kb + c0*8;
    const unsigned short* a1 = xb   + (size_t)(m0 + rb1*64 + lane) * KDIM + kb + c1*8;
    const unsigned short* b0 = Wall + (size_t)(n0 + rb0*64 + lane) * KDIM + kb + c0*8;
    const unsigned short* b1 = Wall + (size_t)(n0 + rb1*64 + lane) * KDIM + kb + c1*8;
    __builtin_amdgcn_global_load_lds((const __attribute__((address_space(1))) unsigned int*)a0,
        (__attribute__((address_space(3))) unsigned int*)(ldsA + (c0*256 + rb0*64)*8), 16, 0, 0);
    __builtin_amdgcn_global_load_lds((const __attribute__((address_space(1))) unsigned int*)a1,
        (__attribute__((address_space(3))) unsigned int*)(ldsA + (c1*256 + rb1*64)*8), 16, 0, 0);
    __builtin_amdgcn_global_load_lds((const __attribute__((address_space(1))) unsigned int*)b0,
        (__attribute__((address_space(3))) unsigned int*)(ldsB + (c0*256 + rb0*64)*8), 16, 0, 0);
    __builtin_amdgcn_global_load_lds((const __attribute__((address_space(1))) unsigned int*)b1,
        (__attribute__((address_space(3))) unsigned int*)(ldsB + (c1*256 + rb1*64)*8), 16, 0, 0);
  };

  // prologue: tiles 0,1 in flight; wait tile 0 landed (tile 1's 4 loads may fly)
  stage(0, 0);
  stage(1, 1);
  asm volatile("s_waitcnt vmcnt(4)" ::: "memory");
  __builtin_amdgcn_s_barrier();

  const int aoff = (lc * 256 + wr * 128 + lr) * 8;   // shorts
  const int boff = (lc * 256 + wc * 64  + lr) * 8;

  int buf = 0;
  for (int kt = 0; kt < NT; ++kt) {
    // prefetch tile kt+2 into the buffer freed at the last barrier
    if (kt + 2 < NT) {
      int db = buf + 2; if (db >= 3) db -= 3;
      stage(kt + 2, db);
    }

    const unsigned short* bufA = &lds[buf * 16384];
    const unsigned short* bufB = bufA + 8192;

    bf16x8 bfrag[4];
    #pragma unroll
    for (int nf = 0; nf < 4; ++nf)
      bfrag[nf] = *(const bf16x8*)(bufB + boff + nf * 128);
    bf16x8 afrag[4];
    #pragma unroll
    for (int mf = 0; mf < 4; ++mf)
      afrag[mf] = *(const bf16x8*)(bufA + aoff + mf * 128);

    __builtin_amdgcn_s_setprio(1);
    #pragma unroll
    for (int mf = 0; mf < 4; ++mf)
      #pragma unroll
      for (int nf = 0; nf < 4; ++nf)
        acc[mf][nf] = __builtin_amdgcn_mfma_f32_16x16x32_bf16(afrag[mf], bfrag[nf], acc[mf][nf], 0, 0, 0);
    __builtin_amdgcn_s_setprio(0);

    #pragma unroll
    for (int mf = 0; mf < 4; ++mf)
      afrag[mf] = *(const bf16x8*)(bufA + aoff + (mf + 4) * 128);

    __builtin_amdgcn_s_setprio(1);
    #pragma unroll
    for (int mf = 0; mf < 4; ++mf)
      #pragma unroll
      for (int nf = 0; nf < 4; ++nf)
        acc[mf + 4][nf] = __builtin_amdgcn_mfma_f32_16x16x32_bf16(afrag[mf], bfrag[nf], acc[mf + 4][nf], 0, 0, 0);
    __builtin_amdgcn_s_setprio(0);

    // counted wait: newest 4 loads (tile kt+2) may stay in flight
    if (kt < NT - 2) asm volatile("s_waitcnt vmcnt(4)" ::: "memory");
    else             asm volatile("s_waitcnt vmcnt(0)" ::: "memory");
    __builtin_amdgcn_s_barrier();
    buf = (buf == 2) ? 0 : buf + 1;
  }

  // epilogue: C/D layout col = lane&15 (within nf), row = 4*(lane>>4)+r (within mf)
  unsigned short* Cout = (n0 < 1024) ? P : Q;
  const int colb = (n0 < 1024) ? n0 : (n0 - 1024);
  const int cb = lane & 15;
  const int rb4 = (lane >> 4) * 4;
  #pragma unroll
  for (int mf = 0; mf < 8; ++mf) {
    #pragma unroll
    for (int nf = 0; nf < 4; ++nf) {
      const size_t col  = (size_t)(colb + wc * 64 + nf * 16 + cb);
      const size_t row0 = (size_t)(m0 + wr * 128 + mf * 16 + rb4);
      #pragma unroll
      for (int r = 0; r < 4; ++r)
        Cout[(row0 + r) * D_MODEL + col] = f2bf(acc[mf][nf][r]);
    }
  }
}

// ---------------- K2: per-chunk scan aggregates (bf16 preacts) -----------------
__global__ __launch_bounds__(256) void k_scan_agg(
    const unsigned short* __restrict__ P, const unsigned short* __restrict__ Q,
    const float* __restrict__ bz, const float* __restrict__ bh,
    float* __restrict__ Aagg, float* __restrict__ Bagg)
{
  int c = blockIdx.x & (NC - 1);
  int b = blockIdx.x >> 7;
  int d = threadIdx.x * 4;
  f32x4 vbz = *(const f32x4*)(bz + d);
  f32x4 vbh = *(const f32x4*)(bh + d);
  f32x4 A = {1.f, 1.f, 1.f, 1.f}, Bv = {0.f, 0.f, 0.f, 0.f};
  size_t base = ((size_t)b * SEQ + (size_t)c * CL) * D_MODEL + d;
  for (int t = 0; t < CL; ++t) {
    u16x4 pu = *(const u16x4*)(P + base + (size_t)t * D_MODEL);
    u16x4 qu = *(const u16x4*)(Q + base + (size_t)t * D_MODEL);
    #pragma unroll
    for (int r = 0; r < 4; ++r) {
      float z = 1.f / (1.f + __expf(-(bf2f(pu[r]) + vbz[r])));
      float a = 1.f - z;
      float bb = z * (bf2f(qu[r]) + vbh[r]);
      Bv[r] = a * Bv[r] + bb;
      A[r]  = a * A[r];
    }
  }
  size_t o = ((size_t)b * NC + c) * D_MODEL + d;
  *(f32x4*)(Aagg + o) = A;
  *(f32x4*)(Bagg + o) = Bv;
}

// ---------------- K3: scan across chunk aggregates ----------------
__global__ __launch_bounds__(256) void k_scan_chunks(
    const float* __restrict__ Aagg, const float* __restrict__ Bagg,
    float* __restrict__ Pref)
{
  int idx = blockIdx.x * 256 + threadIdx.x;  // b*1024 + d
  int b = idx >> 10, d = idx & 1023;
  float h = 0.f;
  for (int cc = 0; cc < NC; ++cc) {
    size_t o = ((size_t)b * NC + cc) * D_MODEL + d;
    Pref[o] = h;
    h = Aagg[o] * h + Bagg[o];
  }
}

// ---------------- K4: apply scan, write fp32 h to d_out ----------------
__global__ __launch_bounds__(256) void k_scan_apply(
    const unsigned short* __restrict__ P, const unsigned short* __restrict__ Q,
    const float* __restrict__ bz, const float* __restrict__ bh,
    const float* __restrict__ Pref, float* __restrict__ out)
{
  int c = blockIdx.x & (NC - 1);
  int b = blockIdx.x >> 7;
  int d = threadIdx.x * 4;
  f32x4 vbz = *(const f32x4*)(bz + d);
  f32x4 vbh = *(const f32x4*)(bh + d);
  f32x4 h = *(const f32x4*)(Pref + ((size_t)b * NC + c) * D_MODEL + d);
  size_t base = ((size_t)b * SEQ + (size_t)c * CL) * D_MODEL + d;
  for (int t = 0; t < CL; ++t) {
    u16x4 pu = *(const u16x4*)(P + base + (size_t)t * D_MODEL);
    u16x4 qu = *(const u16x4*)(Q + base + (size_t)t * D_MODEL);
    #pragma unroll
    for (int r = 0; r < 4; ++r) {
      float z = 1.f / (1.f + __expf(-(bf2f(pu[r]) + vbz[r])));
      float a = 1.f - z;
      h[r] = a * h[r] + z * (bf2f(qu[r]) + vbh[r]);
    }
    *(f32x4*)(out + base + (size_t)t * D_MODEL) = h;
  }
}

extern "C" void kernel_launch(void* const* d_in, const int* in_sizes, int n_in,
                              void* d_out, int out_size, void* d_ws, size_t ws_size,
                              hipStream_t stream)
{
  const float* x  = (const float*)d_in[0];
  const float* Wz = (const float*)d_in[1];
  const float* bz = (const float*)d_in[2];
  const float* Wh = (const float*)d_in[3];
  const float* bh = (const float*)d_in[4];

  char* ws = (char*)d_ws;
  // workspace layout (bytes)
  unsigned short* xb   = (unsigned short*)(ws);               // 33,554,432
  unsigned short* Wall = (unsigned short*)(ws + 33554432);    //  4,194,304 ([WzT;WhT])
  unsigned short* Pb   = (unsigned short*)(ws + 37748736);    // 33,554,432 (z-preact bf16)
  unsigned short* Qb   = (unsigned short*)(ws + 71303168);    // 33,554,432 (h-preact bf16)
  float* Aagg = (float*)(ws + 104857600);                     //  2,097,152
  float* Bagg = (float*)(ws + 106954752);                     //  2,097,152
  float* Pref = (float*)(ws + 109051904);                     //  2,097,152
  float* out  = (float*)d_out;

  k_cvt_x<<<M_TOTAL * D_MODEL / 4 / 256, 256, 0, stream>>>(x, xb);
  k_cvt_wT<<<dim3(32, 32, 2), dim3(32, 8), 0, stream>>>(Wz, Wh, Wall, Wall + (size_t)1024 * 1024);
  k_gemm8<<<dim3(M_TOTAL / BM, NTOT / BN), 512, 0, stream>>>(xb, Wall, Pb, Qb);
  k_scan_agg<<<BATCH * NC, 256, 0, stream>>>(Pb, Qb, bz, bh, Aagg, Bagg);
  k_scan_chunks<<<BATCH * D_MODEL / 256, 256, 0, stream>>>(Aagg, Bagg, Pref);
  k_scan_apply<<<BATCH * NC, 256, 0, stream>>>(Pb, Qb, bz, bh, Pref, out);
}